// Round 1
// baseline (697.593 us; speedup 1.0000x reference)
//
#include <hip/hip_runtime.h>
#include <math.h>

#define B_ 32
#define Q_ 1024
#define G_ 64

// Build transposed float32 cost matrix ct[b][i][j] (i = gt row, j = proposal col),
// exactly matching the reference's f32 arithmetic: (5*(-obj) + 10*cd) + 2*(-giou).
__global__ __launch_bounds__(256) void build_cost_kernel(
    const float* __restrict__ obj, const float* __restrict__ cd,
    const float* __restrict__ gi, float* __restrict__ ct)
{
    __shared__ float tile[64][65];
    const int b  = blockIdx.y;
    const int jb = blockIdx.x << 6;
    for (int tt = threadIdx.x; tt < 64 * 64; tt += 256) {
        const int jj = tt >> 6, ii = tt & 63;       // consecutive threads: consecutive ii
        const int j  = jb + jj;
        const float o = obj[(b << 10) + j];
        const int idx = (((b << 10) + j) << 6) + ii;  // cd/gi: [b][j][i], i contiguous
        const float c = __fadd_rn(
            __fadd_rn(__fmul_rn(5.0f, -o), __fmul_rn(10.0f, cd[idx])),
            __fmul_rn(2.0f, -gi[idx]));
        tile[ii][jj] = c;                            // transposed into LDS (pad 65: conflict-free)
    }
    __syncthreads();
    for (int tt = threadIdx.x; tt < 64 * 64; tt += 256) {
        const int ii = tt >> 6, jj = tt & 63;       // consecutive threads: consecutive jj
        ct[(((b << 6) + ii) << 10) + jb + jj] = tile[ii][jj];  // coalesced writes
    }
}

// One wave (64 lanes) per batch. Exact replication of scipy/np Jonker-Volgenant
// shortest-augmenting-path on the transposed (g x 1024) float64 cost matrix.
template<bool USE_CT>
__global__ __launch_bounds__(64) void matcher_kernel(
    const float* __restrict__ obj, const float* __restrict__ cd,
    const float* __restrict__ gi, const int* __restrict__ ngt,
    const float* __restrict__ ct, float* __restrict__ out_ind,
    float* __restrict__ out_mask)
{
    __shared__ double v_[Q_];
    __shared__ double sh_[Q_];
    __shared__ int    path_[Q_];
    __shared__ int    row4col_[Q_];
    __shared__ int    SC_[Q_];
    __shared__ double u_[G_];
    __shared__ int    col4row_[G_];
    __shared__ int    SR_[G_];

    const int b    = blockIdx.x;
    const int lane = threadIdx.x;
    const int g    = ngt[b];

    for (int j = lane; j < Q_; j += 64) { v_[j] = 0.0; row4col_[j] = -1; }
    u_[lane] = 0.0;
    col4row_[lane] = -1;
    __syncthreads();

    const float* ctb  = USE_CT ? (ct + ((size_t)b << 16)) : (const float*)nullptr;
    const float* objb = obj + (b << 10);
    const float* cdb  = cd + ((size_t)b << 16);
    const float* gib  = gi + ((size_t)b << 16);

    for (int cur = 0; cur < g; ++cur) {
        for (int j = lane; j < Q_; j += 64) {
            sh_[j] = INFINITY; path_[j] = -1; SC_[j] = 0;
        }
        __builtin_amdgcn_wave_barrier();

        double minv = 0.0;   // wave-uniform scalars (replicated per lane)
        int i = cur;
        int nSR = 0;
        int sink = -1;

        while (sink < 0) {
            if (lane == 0) SR_[nSR] = i;
            nSR++;
            const double ui = u_[i];

            double lm = INFINITY;
            int    lj = 0x7fffffff;
            #pragma unroll
            for (int k = 0; k < Q_ / 64; ++k) {
                const int j = lane + (k << 6);       // strided: coalesced + 2-way LDS (free)
                if (SC_[j]) continue;
                float cf;
                if (USE_CT) {
                    cf = ctb[(i << 10) + j];
                } else {
                    const int idx = (j << 6) + i;
                    cf = __fadd_rn(
                        __fadd_rn(__fmul_rn(5.0f, -objb[j]), __fmul_rn(10.0f, cdb[idx])),
                        __fmul_rn(2.0f, -gib[idx]));
                }
                // numpy order: ((min_val + cost) - u[i]) - v[j], float64
                const double r = ((minv + (double)cf) - ui) - v_[j];
                double s = sh_[j];
                if (r < s) { s = r; sh_[j] = r; path_[j] = i; }   // strict <
                if (s < lm) { lm = s; lj = j; }                   // first-min within lane
            }
            // wave argmin; ties -> smaller j (matches np.argmin first occurrence)
            for (int off = 32; off > 0; off >>= 1) {
                const double om = __shfl_xor(lm, off, 64);
                const int    oj = __shfl_xor(lj, off, 64);
                if (om < lm || (om == lm && oj < lj)) { lm = om; lj = oj; }
            }
            minv = lm;
            const int jm = lj;
            if (lane == 0) SC_[jm] = 1;
            __builtin_amdgcn_wave_barrier();
            const int rc = row4col_[jm];
            if (rc < 0) sink = jm; else i = rc;
        }

        // dual updates (numpy order: u/v +/-= (min_val - shortest[...]))
        if (lane == 0) u_[cur] += minv;
        for (int t = lane; t < nSR; t += 64) {
            const int irow = SR_[t];
            if (irow != cur) u_[irow] += minv - sh_[col4row_[irow]];
        }
        for (int j = lane; j < Q_; j += 64) {
            if (SC_[j]) v_[j] -= minv - sh_[j];
        }
        __builtin_amdgcn_wave_barrier();

        // augment along alternating path (serial, tiny)
        if (lane == 0) {
            int j = sink;
            while (true) {
                const int ii = path_[j];
                row4col_[j] = ii;
                const int nj = col4row_[ii];
                col4row_[ii] = j;
                j = nj;
                if (ii == cur) break;
            }
        }
        __builtin_amdgcn_wave_barrier();
    }

    // Outputs: per_prop_gt_inds then proposal_matched_mask, both f32, zero when unmatched.
    for (int j = lane; j < Q_; j += 64) {
        const int rc = row4col_[j];
        out_ind [(b << 10) + j] = (rc >= 0) ? (float)rc : 0.0f;
        out_mask[(b << 10) + j] = (rc >= 0) ? 1.0f : 0.0f;
    }
}

extern "C" void kernel_launch(void* const* d_in, const int* in_sizes, int n_in,
                              void* d_out, int out_size, void* d_ws, size_t ws_size,
                              hipStream_t stream)
{
    // inputs: 0 sem_cls_prob (unused), 1 objectness_prob, 2 center_dist, 3 gious, 4 nactual_gt
    const float* obj = (const float*)d_in[1];
    const float* cd  = (const float*)d_in[2];
    const float* gi  = (const float*)d_in[3];
    const int*   ngt = (const int*)d_in[4];
    float* out0 = (float*)d_out;            // per_prop_gt_inds as float
    float* out1 = out0 + B_ * Q_;           // proposal_matched_mask

    const size_t ct_bytes = (size_t)B_ * G_ * Q_ * sizeof(float);
    if (ws_size >= ct_bytes) {
        float* ct = (float*)d_ws;
        build_cost_kernel<<<dim3(Q_ / 64, B_), 256, 0, stream>>>(obj, cd, gi, ct);
        matcher_kernel<true><<<B_, 64, 0, stream>>>(obj, cd, gi, ngt, ct, out0, out1);
    } else {
        matcher_kernel<false><<<B_, 64, 0, stream>>>(obj, cd, gi, ngt, nullptr, out0, out1);
    }
}

// Round 2
// 286.827 us; speedup vs baseline: 2.4321x; 2.4321x over previous
//
#include <hip/hip_runtime.h>
#include <math.h>

#define B_ 32
#define Q_ 1024
#define G_ 64
#define K_ 16   // columns per lane (Q_ / 64)

// Build transposed float32 cost matrix ct[b][i][j] (i = gt row, j = proposal col),
// exactly matching the reference's f32 arithmetic: (5*(-obj) + 10*cd) + 2*(-giou).
__global__ __launch_bounds__(256) void build_cost_kernel(
    const float* __restrict__ obj, const float* __restrict__ cd,
    const float* __restrict__ gi, float* __restrict__ ct)
{
    __shared__ float tile[64][65];
    const int b  = blockIdx.y;
    const int jb = blockIdx.x << 6;
    for (int tt = threadIdx.x; tt < 64 * 64; tt += 256) {
        const int jj = tt >> 6, ii = tt & 63;       // consecutive threads: consecutive ii
        const int j  = jb + jj;
        const float o = obj[(b << 10) + j];
        const int idx = (((b << 10) + j) << 6) + ii;  // cd/gi: [b][j][i], i contiguous
        const float c = __fadd_rn(
            __fadd_rn(__fmul_rn(5.0f, -o), __fmul_rn(10.0f, cd[idx])),
            __fmul_rn(2.0f, -gi[idx]));
        tile[ii][jj] = c;                            // transposed into LDS (pad 65: conflict-free)
    }
    __syncthreads();
    for (int tt = threadIdx.x; tt < 64 * 64; tt += 256) {
        const int ii = tt >> 6, jj = tt & 63;       // consecutive threads: consecutive jj
        ct[(((b << 6) + ii) << 10) + jb + jj] = tile[ii][jj];  // coalesced writes
    }
}

// Broadcast a double from a wave-uniform source lane via readlane (scalar, fast).
__device__ __forceinline__ double readlane_f64(double x, int srclane) {
    const int sl = __builtin_amdgcn_readfirstlane(srclane);
    union { double d; int i2[2]; } a; a.d = x;
    const int lo = __builtin_amdgcn_readlane(a.i2[0], sl);
    const int hi = __builtin_amdgcn_readlane(a.i2[1], sl);
    union { int i2[2]; double d; } r; r.i2[0] = lo; r.i2[1] = hi;
    return r.d;
}

// One wave (64 lanes) per batch. Register-resident Jonker-Volgenant:
// lane L owns columns j = L + 64k (k<16): v[k], shortest[k], SC-bit k in regs.
// lane L owns u[row=L] and a mirror of col4row[row=L] in regs.
// LDS only for: row4col (1 read/step), path (conditional writes), augment, rare gather.
template<bool USE_CT>
__global__ __launch_bounds__(64) void matcher_kernel(
    const float* __restrict__ obj, const float* __restrict__ cd,
    const float* __restrict__ gi, const int* __restrict__ ngt,
    const float* __restrict__ ct, float* __restrict__ out_ind,
    float* __restrict__ out_mask)
{
    __shared__ int    row4col_[Q_];
    __shared__ int    path_[Q_];
    __shared__ int    col4row_[G_];
    __shared__ double sh_lds[Q_];   // only touched when a Dijkstra takes >1 step

    const int b    = blockIdx.x;
    const int lane = threadIdx.x;
    const int g    = ngt[b];

    for (int j = lane; j < Q_; j += 64) row4col_[j] = -1;
    col4row_[lane] = -1;
    double u_r = 0.0;          // u[lane]
    int col4row_r = -1;        // col4row[lane] register mirror
    double v_r[K_];
    #pragma unroll
    for (int k = 0; k < K_; ++k) v_r[k] = 0.0;
    __syncthreads();

    const float* ctb  = USE_CT ? (ct + ((size_t)b << 16)) : (const float*)nullptr;
    const float* objb = obj + (b << 10);
    const float* cdb  = cd + ((size_t)b << 16);
    const float* gib  = gi + ((size_t)b << 16);

    // Fallback path: obj term is row-independent; precompute 5*(-obj[j]).
    float objm[K_];
    if (!USE_CT) {
        #pragma unroll
        for (int k = 0; k < K_; ++k) objm[k] = __fmul_rn(5.0f, -objb[lane + (k << 6)]);
    }

    // cost row loader (exact f32 arithmetic in both paths)
    auto load_row = [&](int i, float* c_row) {
        if (USE_CT) {
            #pragma unroll
            for (int k = 0; k < K_; ++k) c_row[k] = ctb[(i << 10) + lane + (k << 6)];
        } else {
            #pragma unroll
            for (int k = 0; k < K_; ++k) {
                const int j = lane + (k << 6);
                const int idx = (j << 6) + i;
                c_row[k] = __fadd_rn(__fadd_rn(objm[k], __fmul_rn(10.0f, cdb[idx])),
                                     __fmul_rn(2.0f, -gib[idx]));
            }
        }
    };

    float c_row[K_];
    if (g > 0) load_row(0, c_row);   // prefetch row 0

    for (int cur = 0; cur < g; ++cur) {
        double sh_r[K_];
        #pragma unroll
        for (int k = 0; k < K_; ++k) sh_r[k] = (double)INFINITY;
        unsigned sc = 0u;
        bool inSR = (lane == cur);
        int nSR = 0;
        double minv = 0.0;
        int i = cur;
        int sink = -1;
        double ui = readlane_f64(u_r, i);

        while (sink < 0) {
            ++nSR;
            double lm = (double)INFINITY;
            int    lj = 0x7fffffff;
            #pragma unroll
            for (int k = 0; k < K_; ++k) {
                if (!(sc & (1u << k))) {
                    // numpy order: ((min_val + cost) - u[i]) - v[j], float64
                    const double r = ((minv + (double)c_row[k]) - ui) - v_r[k];
                    if (r < sh_r[k]) {                    // strict <
                        sh_r[k] = r;
                        path_[lane + (k << 6)] = i;       // write-only, off critical path
                    }
                    const double s = sh_r[k];
                    if (s < lm) { lm = s; lj = lane + (k << 6); }  // first-min in-lane
                }
            }
            // wave argmin; ties -> smaller j (np.argmin first occurrence)
            for (int off = 32; off > 0; off >>= 1) {
                const double om = __shfl_xor(lm, off, 64);
                const int    oj = __shfl_xor(lj, off, 64);
                if (om < lm || (om == lm && oj < lj)) { lm = om; lj = oj; }
            }
            minv = lm;
            const int jm = lj;
            if (lane == (jm & 63)) sc |= (1u << (jm >> 6));
            __builtin_amdgcn_wave_barrier();
            const int rc = row4col_[jm];       // uniform addr -> LDS broadcast
            if (rc < 0) {
                sink = jm;
            } else {
                i = rc;
                if (lane == i) inSR = true;
                ui = readlane_f64(u_r, i);
                load_row(i, c_row);            // rare (multi-step Dijkstra)
            }
        }

        // dual updates (before augment, as in reference)
        if (lane == cur) u_r += minv;
        if (nSR > 1) {
            #pragma unroll
            for (int k = 0; k < K_; ++k) sh_lds[lane + (k << 6)] = sh_r[k];
            __builtin_amdgcn_wave_barrier();
            if (inSR && lane != cur) u_r += minv - sh_lds[col4row_r];
            __builtin_amdgcn_wave_barrier();
        }
        #pragma unroll
        for (int k = 0; k < K_; ++k) {
            if (sc & (1u << k)) v_r[k] -= minv - sh_r[k];
        }

        // augment along alternating path (uniform control, lane0 does LDS writes)
        {
            int j = sink;
            while (true) {
                const int ii = path_[j];       // uniform addr broadcast
                const int nj = col4row_[ii];   // read old value BEFORE overwrite
                if (lane == 0) { row4col_[j] = ii; col4row_[ii] = j; }
                if (lane == ii) col4row_r = j;
                __builtin_amdgcn_wave_barrier();
                j = nj;
                if (ii == cur) break;
            }
        }

        // prefetch next row's costs (hides L2/HBM latency behind loop tail)
        if (cur + 1 < g) load_row(cur + 1, c_row);
        __builtin_amdgcn_wave_barrier();
    }

    // Outputs: per_prop_gt_inds then proposal_matched_mask, both f32, zero unmatched.
    for (int j = lane; j < Q_; j += 64) {
        const int rc = row4col_[j];
        out_ind [(b << 10) + j] = (rc >= 0) ? (float)rc : 0.0f;
        out_mask[(b << 10) + j] = (rc >= 0) ? 1.0f : 0.0f;
    }
}

extern "C" void kernel_launch(void* const* d_in, const int* in_sizes, int n_in,
                              void* d_out, int out_size, void* d_ws, size_t ws_size,
                              hipStream_t stream)
{
    // inputs: 0 sem_cls_prob (unused), 1 objectness_prob, 2 center_dist, 3 gious, 4 nactual_gt
    const float* obj = (const float*)d_in[1];
    const float* cd  = (const float*)d_in[2];
    const float* gi  = (const float*)d_in[3];
    const int*   ngt = (const int*)d_in[4];
    float* out0 = (float*)d_out;            // per_prop_gt_inds as float
    float* out1 = out0 + B_ * Q_;           // proposal_matched_mask

    const size_t ct_bytes = (size_t)B_ * G_ * Q_ * sizeof(float);
    if (ws_size >= ct_bytes) {
        float* ct = (float*)d_ws;
        build_cost_kernel<<<dim3(Q_ / 64, B_), 256, 0, stream>>>(obj, cd, gi, ct);
        matcher_kernel<true><<<B_, 64, 0, stream>>>(obj, cd, gi, ngt, ct, out0, out1);
    } else {
        matcher_kernel<false><<<B_, 64, 0, stream>>>(obj, cd, gi, ngt, nullptr, out0, out1);
    }
}

// Round 3
// 251.710 us; speedup vs baseline: 2.7714x; 1.1395x over previous
//
#include <hip/hip_runtime.h>
#include <math.h>

#define B_ 32
#define Q_ 1024
#define G_ 64
#define K_ 16   // columns per lane (Q_ / 64)

// Build transposed float32 cost matrix ct[b][i][j] (i = gt row, j = proposal col),
// exactly matching the reference's f32 arithmetic: (5*(-obj) + 10*cd) + 2*(-giou).
__global__ __launch_bounds__(256) void build_cost_kernel(
    const float* __restrict__ obj, const float* __restrict__ cd,
    const float* __restrict__ gi, float* __restrict__ ct)
{
    __shared__ float tile[64][65];
    const int b  = blockIdx.y;
    const int jb = blockIdx.x << 6;
    for (int tt = threadIdx.x; tt < 64 * 64; tt += 256) {
        const int jj = tt >> 6, ii = tt & 63;
        const int j  = jb + jj;
        const float o = obj[(b << 10) + j];
        const int idx = (((b << 10) + j) << 6) + ii;
        const float c = __fadd_rn(
            __fadd_rn(__fmul_rn(5.0f, -o), __fmul_rn(10.0f, cd[idx])),
            __fmul_rn(2.0f, -gi[idx]));
        tile[ii][jj] = c;
    }
    __syncthreads();
    for (int tt = threadIdx.x; tt < 64 * 64; tt += 256) {
        const int ii = tt >> 6, jj = tt & 63;
        ct[(((b << 6) + ii) << 10) + jb + jj] = tile[ii][jj];
    }
}

// ---- cross-lane helpers -------------------------------------------------
// row_ror:N DPP = rotation within each 16-lane row: every source lane valid,
// so old/bound_ctrl semantics never apply (we pass old = x, bound_ctrl=false).
template<int CTRL>
__device__ __forceinline__ int dpp_i32(int x) {
    return __builtin_amdgcn_update_dpp(x, x, CTRL, 0xF, 0xF, false);
}
template<int CTRL>
__device__ __forceinline__ double dpp_f64(double x) {
    union { double d; int i[2]; } a; a.d = x;
    union { int i[2]; double d; } r;
    r.i[0] = __builtin_amdgcn_update_dpp(a.i[0], a.i[0], CTRL, 0xF, 0xF, false);
    r.i[1] = __builtin_amdgcn_update_dpp(a.i[1], a.i[1], CTRL, 0xF, 0xF, false);
    return r.d;
}
#define ROR1 0x121
#define ROR2 0x122
#define ROR4 0x124
#define ROR8 0x128

__device__ __forceinline__ double readlane_f64(double x, int sl) {
    union { double d; int i2[2]; } a; a.d = x;
    const int lo = __builtin_amdgcn_readlane(a.i2[0], sl);
    const int hi = __builtin_amdgcn_readlane(a.i2[1], sl);
    union { int i2[2]; double d; } r; r.i2[0] = lo; r.i2[1] = hi;
    return r.d;
}

// uniform-index select from a 16-entry register array
__device__ __forceinline__ int sel16(const int* p, int s) {
    int v = p[0];
#pragma unroll
    for (int k = 1; k < K_; ++k) v = (s == k) ? p[k] : v;
    return v;
}

// One wave (64 lanes) per batch. Fully register-resident Jonker-Volgenant:
// lane L owns columns j = L + 64k (k<16): v, shortest, SC-bit, path, asg-bit in regs.
// lane L owns u[row=L] and col4row[row=L] in regs. Argmin via DPP row_ror +
// readlane combine (no DS on the step critical path).
template<bool USE_CT>
__global__ __launch_bounds__(64) void matcher_kernel(
    const float* __restrict__ obj, const float* __restrict__ cd,
    const float* __restrict__ gi, const int* __restrict__ ngt,
    const float* __restrict__ ct, float* __restrict__ out_ind,
    float* __restrict__ out_mask)
{
    __shared__ int    row4col_[Q_];   // for rare non-sink hop + final output
    __shared__ double sh_lds[Q_];     // only touched when a Dijkstra takes >1 step

    const int b    = blockIdx.x;
    const int lane = threadIdx.x;
    const int g    = ngt[b];

    for (int j = lane; j < Q_; j += 64) row4col_[j] = -1;
    double u_r = 0.0;           // u[lane]
    int col4row_r = -1;         // col4row[lane]
    unsigned asg = 0u;          // bit k: column lane+64k assigned
    double v_r[K_];
    int path_r[K_];
#pragma unroll
    for (int k = 0; k < K_; ++k) { v_r[k] = 0.0; path_r[k] = 0; }
    __builtin_amdgcn_wave_barrier();

    const float* ctb  = USE_CT ? (ct + ((size_t)b << 16)) : (const float*)nullptr;
    const float* objb = obj + (b << 10);
    const float* cdb  = cd + ((size_t)b << 16);
    const float* gib  = gi + ((size_t)b << 16);

    float objm[K_];
    if (!USE_CT) {
#pragma unroll
        for (int k = 0; k < K_; ++k) objm[k] = __fmul_rn(5.0f, -objb[lane + (k << 6)]);
    }

    auto load_row = [&](int i, float* c) {
        if (USE_CT) {
#pragma unroll
            for (int k = 0; k < K_; ++k) c[k] = ctb[(i << 10) + lane + (k << 6)];
        } else {
#pragma unroll
            for (int k = 0; k < K_; ++k) {
                const int j = lane + (k << 6);
                const int idx = (j << 6) + i;
                c[k] = __fadd_rn(__fadd_rn(objm[k], __fmul_rn(10.0f, cdb[idx])),
                                 __fmul_rn(2.0f, -gib[idx]));
            }
        }
    };

    const double INF = __builtin_inf();
    float c_row[K_], c_next[K_];
    if (g > 0) load_row(0, c_row);

    for (int cur = 0; cur < g; ++cur) {
        // prefetch next row at ROW START: whole row's work hides the latency
        const int nxt = (cur + 1 < g) ? cur + 1 : cur;
        load_row(nxt, c_next);

        double sh_r[K_];
#pragma unroll
        for (int k = 0; k < K_; ++k) sh_r[k] = INF;
        unsigned sc = 0u;
        bool inSR = (lane == cur);
        int nSR = 0;
        double minv = 0.0;
        int i = cur;
        int sink = -1;
        double ui = readlane_f64(u_r, i);

        while (sink < 0) {
            ++nSR;
            // ---- scan own 16 columns (exact numpy f64 order) ----
            double cand[K_];
#pragma unroll
            for (int k = 0; k < K_; ++k) {
                const double r = ((minv + (double)c_row[k]) - ui) - v_r[k];
                const bool notSC = !((sc >> k) & 1u);
                const bool upd = notSC && (r < sh_r[k]);     // strict <
                sh_r[k]   = upd ? r : sh_r[k];
                path_r[k] = upd ? i : path_r[k];
                cand[k] = notSC ? sh_r[k] : INF;
            }
            // ---- in-lane min tree, ties -> smaller k (= smaller j) ----
            double tv[8]; int tk[8];
#pragma unroll
            for (int k = 0; k < 8; ++k) {
                const bool t = cand[2 * k + 1] < cand[2 * k];
                tv[k] = t ? cand[2 * k + 1] : cand[2 * k];
                tk[k] = t ? 2 * k + 1 : 2 * k;
            }
#pragma unroll
            for (int k = 0; k < 4; ++k) {
                const bool t = tv[2 * k + 1] < tv[2 * k];
                tv[k] = t ? tv[2 * k + 1] : tv[2 * k];
                tk[k] = t ? tk[2 * k + 1] : tk[2 * k];
            }
#pragma unroll
            for (int k = 0; k < 2; ++k) {
                const bool t = tv[2 * k + 1] < tv[2 * k];
                tv[k] = t ? tv[2 * k + 1] : tv[2 * k];
                tk[k] = t ? tk[2 * k + 1] : tk[2 * k];
            }
            const bool tt = tv[1] < tv[0];
            const double lm = tt ? tv[1] : tv[0];
            const int    lj = lane + ((tt ? tk[1] : tk[0]) << 6);

            // ---- cross-lane value min: 4 DPP rors (row of 16) + readlane x4 ----
            double x = lm, o;
            o = dpp_f64<ROR1>(x); x = (o < x) ? o : x;
            o = dpp_f64<ROR2>(x); x = (o < x) ? o : x;
            o = dpp_f64<ROR4>(x); x = (o < x) ? o : x;
            o = dpp_f64<ROR8>(x); x = (o < x) ? o : x;
            const double g0 = readlane_f64(x, 0),  g1 = readlane_f64(x, 16);
            const double g2 = readlane_f64(x, 32), g3 = readlane_f64(x, 48);
            double gmin = (g1 < g0) ? g1 : g0;
            gmin = (g2 < gmin) ? g2 : gmin;
            gmin = (g3 < gmin) ? g3 : gmin;

            // ---- index min over lanes whose value == gmin (smallest j wins) ----
            int ci = (lm == gmin) ? lj : 0x7fffffff, oi;
            oi = dpp_i32<ROR1>(ci); ci = (oi < ci) ? oi : ci;
            oi = dpp_i32<ROR2>(ci); ci = (oi < ci) ? oi : ci;
            oi = dpp_i32<ROR4>(ci); ci = (oi < ci) ? oi : ci;
            oi = dpp_i32<ROR8>(ci); ci = (oi < ci) ? oi : ci;
            int jm = __builtin_amdgcn_readlane(ci, 0);
            const int j1 = __builtin_amdgcn_readlane(ci, 16);
            const int j2 = __builtin_amdgcn_readlane(ci, 32);
            const int j3 = __builtin_amdgcn_readlane(ci, 48);
            jm = (j1 < jm) ? j1 : jm;
            jm = (j2 < jm) ? j2 : jm;
            jm = (j3 < jm) ? j3 : jm;

            minv = gmin;
            const int owner = jm & 63, slot = jm >> 6;
            if (lane == owner) sc |= (1u << slot);
            const unsigned ownerAsg = (unsigned)__builtin_amdgcn_readlane((int)asg, owner);
            if (!((ownerAsg >> slot) & 1u)) {
                sink = jm;
            } else {
                i = row4col_[jm];                 // rare: multi-step only
                if (lane == i) inSR = true;
                ui = readlane_f64(u_r, i);
                load_row(i, c_row);
            }
        }

        // ---- dual updates (reference order: u, then v, then augment) ----
        if (lane == cur) u_r += minv;
        if (nSR > 1) {
#pragma unroll
            for (int k = 0; k < K_; ++k) sh_lds[lane + (k << 6)] = sh_r[k];
            __builtin_amdgcn_wave_barrier();
            if (inSR && lane != cur) u_r += minv - sh_lds[col4row_r];
            __builtin_amdgcn_wave_barrier();
        }
#pragma unroll
        for (int k = 0; k < K_; ++k) {
            const double w = v_r[k] - (minv - sh_r[k]);
            v_r[k] = ((sc >> k) & 1u) ? w : v_r[k];
        }

        // ---- augment (registers + readlanes; one LDS write per path node) ----
        {
            int j = sink;
            while (true) {
                const int s_owner = j & 63, s_slot = j >> 6;
                const int ii = __builtin_amdgcn_readlane(sel16(path_r, s_slot), s_owner);
                const int nj = __builtin_amdgcn_readlane(col4row_r, ii);  // old value
                if (lane == 0) row4col_[j] = ii;
                if (lane == s_owner) asg |= (1u << s_slot);
                if (lane == ii) col4row_r = j;
                j = nj;
                if (ii == cur) break;
            }
        }

        // next row's costs (prefetched at row start; wait is long hidden)
#pragma unroll
        for (int k = 0; k < K_; ++k) c_row[k] = c_next[k];
        __builtin_amdgcn_wave_barrier();
    }

    __builtin_amdgcn_wave_barrier();
    for (int j = lane; j < Q_; j += 64) {
        const int rc = row4col_[j];
        out_ind [(b << 10) + j] = (rc >= 0) ? (float)rc : 0.0f;
        out_mask[(b << 10) + j] = (rc >= 0) ? 1.0f : 0.0f;
    }
}

extern "C" void kernel_launch(void* const* d_in, const int* in_sizes, int n_in,
                              void* d_out, int out_size, void* d_ws, size_t ws_size,
                              hipStream_t stream)
{
    const float* obj = (const float*)d_in[1];
    const float* cd  = (const float*)d_in[2];
    const float* gi  = (const float*)d_in[3];
    const int*   ngt = (const int*)d_in[4];
    float* out0 = (float*)d_out;
    float* out1 = out0 + B_ * Q_;

    const size_t ct_bytes = (size_t)B_ * G_ * Q_ * sizeof(float);
    if (ws_size >= ct_bytes) {
        float* ct = (float*)d_ws;
        build_cost_kernel<<<dim3(Q_ / 64, B_), 256, 0, stream>>>(obj, cd, gi, ct);
        matcher_kernel<true><<<B_, 64, 0, stream>>>(obj, cd, gi, ngt, ct, out0, out1);
    } else {
        matcher_kernel<false><<<B_, 64, 0, stream>>>(obj, cd, gi, ngt, nullptr, out0, out1);
    }
}

// Round 4
// 214.546 us; speedup vs baseline: 3.2515x; 1.1732x over previous
//
#include <hip/hip_runtime.h>
#include <math.h>

#define B_ 32
#define Q_ 1024
#define G_ 64
#define T_ 256   // threads per batch (4 waves)
#define K4 4     // columns per thread (Q_ / T_)

// Build transposed float32 cost matrix ct[b][i][j] (i = gt row, j = proposal col),
// exactly matching the reference's f32 arithmetic: (5*(-obj) + 10*cd) + 2*(-giou).
__global__ __launch_bounds__(256) void build_cost_kernel(
    const float* __restrict__ obj, const float* __restrict__ cd,
    const float* __restrict__ gi, float* __restrict__ ct)
{
    __shared__ float tile[64][65];
    const int b  = blockIdx.y;
    const int jb = blockIdx.x << 6;
    for (int tt = threadIdx.x; tt < 64 * 64; tt += 256) {
        const int jj = tt >> 6, ii = tt & 63;
        const int j  = jb + jj;
        const float o = obj[(b << 10) + j];
        const int idx = (((b << 10) + j) << 6) + ii;
        const float c = __fadd_rn(
            __fadd_rn(__fmul_rn(5.0f, -o), __fmul_rn(10.0f, cd[idx])),
            __fmul_rn(2.0f, -gi[idx]));
        tile[ii][jj] = c;
    }
    __syncthreads();
    for (int tt = threadIdx.x; tt < 64 * 64; tt += 256) {
        const int ii = tt >> 6, jj = tt & 63;
        ct[(((b << 6) + ii) << 10) + jb + jj] = tile[ii][jj];
    }
}

// ---- cross-lane helpers -------------------------------------------------
// row_ror:N DPP rotates within each 16-lane row; all source lanes valid.
template<int CTRL>
__device__ __forceinline__ int dpp_i32(int x) {
    return __builtin_amdgcn_update_dpp(x, x, CTRL, 0xF, 0xF, false);
}
template<int CTRL>
__device__ __forceinline__ double dpp_f64(double x) {
    union { double d; int i[2]; } a; a.d = x;
    union { int i[2]; double d; } r;
    r.i[0] = __builtin_amdgcn_update_dpp(a.i[0], a.i[0], CTRL, 0xF, 0xF, false);
    r.i[1] = __builtin_amdgcn_update_dpp(a.i[1], a.i[1], CTRL, 0xF, 0xF, false);
    return r.d;
}
#define ROR1 0x121
#define ROR2 0x122
#define ROR4 0x124
#define ROR8 0x128

__device__ __forceinline__ double readlane_f64(double x, int sl) {
    const int s = __builtin_amdgcn_readfirstlane(sl);
    union { double d; int i2[2]; } a; a.d = x;
    union { int i2[2]; double d; } r;
    r.i2[0] = __builtin_amdgcn_readlane(a.i2[0], s);
    r.i2[1] = __builtin_amdgcn_readlane(a.i2[1], s);
    return r.d;
}
__device__ __forceinline__ int readlane_i32(int x, int sl) {
    return __builtin_amdgcn_readlane(x, __builtin_amdgcn_readfirstlane(sl));
}

// 4 waves per batch; thread t owns columns j = t + 256k (k<4).
// Register state: v, shortest, SC-bits, costs per thread; u / col4row / asg are
// lane-keyed replicas identical in every wave (updated from wave-uniform values).
// LDS: per-step 4-slot (val,idx) combine (parity double-buffered, 1 barrier/step),
// path, row4col (hops + output), sh dump for multi-step dual updates.
template<bool USE_CT>
__global__ __launch_bounds__(256) void matcher_kernel(
    const float* __restrict__ obj, const float* __restrict__ cd,
    const float* __restrict__ gi, const int* __restrict__ ngt,
    const float* __restrict__ ct, float* __restrict__ out_ind,
    float* __restrict__ out_mask)
{
    __shared__ int    row4col_[Q_];
    __shared__ int    path_[Q_];
    __shared__ double sh_lds[Q_];
    __shared__ double comb_v[2][4];
    __shared__ int    comb_j[2][4];

    const int b = blockIdx.x;
    const int t = threadIdx.x;
    const int l = t & 63;        // lane within wave
    const int w = t >> 6;        // wave id
    const int g = ngt[b];

    for (int j = t; j < Q_; j += T_) row4col_[j] = -1;
    double u_rep   = 0.0;        // u[l], replicated per wave
    int    c4r_rep = -1;         // col4row[l], replicated per wave
    unsigned asg   = 0u;         // bit s: column l + 64s assigned (replicated)
    double v_r[K4];
    #pragma unroll
    for (int k = 0; k < K4; ++k) v_r[k] = 0.0;
    __syncthreads();

    const float* ctb  = USE_CT ? (ct + ((size_t)b << 16)) : (const float*)nullptr;
    const float* objb = obj + (b << 10);
    const float* cdb  = cd + ((size_t)b << 16);
    const float* gib  = gi + ((size_t)b << 16);

    float objm[K4];
    if (!USE_CT) {
        #pragma unroll
        for (int k = 0; k < K4; ++k) objm[k] = __fmul_rn(5.0f, -objb[t + (k << 8)]);
    }
    auto load_row = [&](int i, float* c) {
        if (USE_CT) {
            #pragma unroll
            for (int k = 0; k < K4; ++k) c[k] = ctb[(i << 10) + t + (k << 8)];
        } else {
            #pragma unroll
            for (int k = 0; k < K4; ++k) {
                const int j = t + (k << 8);
                const int idx = (j << 6) + i;
                c[k] = __fadd_rn(__fadd_rn(objm[k], __fmul_rn(10.0f, cdb[idx])),
                                 __fmul_rn(2.0f, -gib[idx]));
            }
        }
    };

    const double INF = __builtin_inf();
    float c_row[K4], c_next[K4];
    unsigned stepctr = 0;
    if (g > 0) load_row(0, c_row);

    for (int cur = 0; cur < g; ++cur) {
        const int nxt = (cur + 1 < g) ? cur + 1 : cur;
        load_row(nxt, c_next);                 // prefetch next row at row start

        double sh_r[K4];
        #pragma unroll
        for (int k = 0; k < K4; ++k) sh_r[k] = INF;
        unsigned sc = 0u;
        bool inSR = (l == cur);
        int nSR = 0;
        double minv = 0.0;
        int i = cur;
        int sink = -1;
        double ui = readlane_f64(u_rep, i);

        while (sink < 0) {
            ++nSR;
            // ---- scan own 4 columns (exact numpy f64 order) ----
            double cand[K4];
            #pragma unroll
            for (int k = 0; k < K4; ++k) {
                const double r = ((minv + (double)c_row[k]) - ui) - v_r[k];
                const bool notSC = !((sc >> k) & 1u);
                const bool upd = notSC && (r < sh_r[k]);   // strict <
                sh_r[k] = upd ? r : sh_r[k];
                if (upd) path_[t + (k << 8)] = i;          // off critical path
                cand[k] = notSC ? sh_r[k] : INF;
            }
            // ---- in-thread lex min (ties -> smaller k = smaller j) ----
            double bv0 = cand[0]; int bj0 = t;
            if (cand[1] < bv0) { bv0 = cand[1]; bj0 = t + 256; }
            double bv1 = cand[2]; int bj1 = t + 512;
            if (cand[3] < bv1) { bv1 = cand[3]; bj1 = t + 768; }
            double bv = bv0; int bj = bj0;
            if (bv1 < bv0) { bv = bv1; bj = bj1; }
            // ---- in-wave lex min: 4 DPP rors + 4-group readlane combine ----
            #pragma unroll
            for (int rr = 0; rr < 4; ++rr) {
                double ov; int oj;
                if (rr == 0)      { ov = dpp_f64<ROR1>(bv); oj = dpp_i32<ROR1>(bj); }
                else if (rr == 1) { ov = dpp_f64<ROR2>(bv); oj = dpp_i32<ROR2>(bj); }
                else if (rr == 2) { ov = dpp_f64<ROR4>(bv); oj = dpp_i32<ROR4>(bj); }
                else              { ov = dpp_f64<ROR8>(bv); oj = dpp_i32<ROR8>(bj); }
                const bool take = (ov < bv) || (ov == bv && oj < bj);
                bv = take ? ov : bv;
                bj = take ? oj : bj;
            }
            #pragma unroll
            for (int gg = 1; gg < 4; ++gg) {
                const double ov = readlane_f64(bv, gg << 4);
                const int    oj = readlane_i32(bj, gg << 4);
                const bool take = (ov < bv) || (ov == bv && oj < bj);
                bv = take ? ov : bv;
                bj = take ? oj : bj;
            }
            // lane 0 of each wave now holds the wave min (value uniform via lane0 read)
            const double wv = readlane_f64(bv, 0);
            const int    wj = readlane_i32(bj, 0);
            // ---- cross-wave combine: parity-buffered slots, ONE barrier/step ----
            const int par = stepctr & 1; ++stepctr;
            if (l == 0) { comb_v[par][w] = wv; comb_j[par][w] = wj; }
            __syncthreads();
            double mv = comb_v[par][0]; int mj = comb_j[par][0];
            #pragma unroll
            for (int w2 = 1; w2 < 4; ++w2) {
                const double ov = comb_v[par][w2];
                const int    oj = comb_j[par][w2];
                const bool take = (ov < mv) || (ov == mv && oj < mj);
                mv = take ? ov : mv;
                mj = take ? oj : mj;
            }
            minv = mv;
            const int jm = mj;
            if (t == (jm & 255)) sc |= (1u << (jm >> 8));
            const int owner = jm & 63, slot = jm >> 6;
            const unsigned ownerAsg = (unsigned)readlane_i32((int)asg, owner);
            if (!((ownerAsg >> slot) & 1u)) {
                sink = jm;
            } else {
                i = row4col_[jm];              // rare: multi-step only
                if (l == i) inSR = true;
                ui = readlane_f64(u_rep, i);
                load_row(i, c_row);
            }
        }

        // ---- dual updates (reference order: u, then v, then augment) ----
        if (l == cur) u_rep += minv;
        if (nSR > 1) {
            #pragma unroll
            for (int k = 0; k < K4; ++k) sh_lds[t + (k << 8)] = sh_r[k];
            __syncthreads();
            if (inSR && l != cur) u_rep += minv - sh_lds[c4r_rep];
        }
        #pragma unroll
        for (int k = 0; k < K4; ++k) {
            const double nv = v_r[k] - (minv - sh_r[k]);
            v_r[k] = ((sc >> k) & 1u) ? nv : v_r[k];
        }

        // ---- augment: all waves traverse (reads hit only pre-augment values);
        //      thread 0 writes LDS; every wave updates its replicas ----
        {
            int j = sink;
            while (true) {
                const int ii = path_[j];                     // uniform LDS read
                const int nj = readlane_i32(c4r_rep, ii);    // old col4row[ii]
                if (t == 0) row4col_[j] = ii;
                if (l == ii) c4r_rep = j;
                if (l == (j & 63)) asg |= 1u << (j >> 6);
                j = nj;
                if (ii == cur) break;
            }
        }

        #pragma unroll
        for (int k = 0; k < K4; ++k) c_row[k] = c_next[k];
        __syncthreads();   // row end: row4col_/path_ visibility for next row
    }

    for (int j = t; j < Q_; j += T_) {
        const int rc = row4col_[j];
        out_ind [(b << 10) + j] = (rc >= 0) ? (float)rc : 0.0f;
        out_mask[(b << 10) + j] = (rc >= 0) ? 1.0f : 0.0f;
    }
}

extern "C" void kernel_launch(void* const* d_in, const int* in_sizes, int n_in,
                              void* d_out, int out_size, void* d_ws, size_t ws_size,
                              hipStream_t stream)
{
    const float* obj = (const float*)d_in[1];
    const float* cd  = (const float*)d_in[2];
    const float* gi  = (const float*)d_in[3];
    const int*   ngt = (const int*)d_in[4];
    float* out0 = (float*)d_out;
    float* out1 = out0 + B_ * Q_;

    const size_t ct_bytes = (size_t)B_ * G_ * Q_ * sizeof(float);
    if (ws_size >= ct_bytes) {
        float* ct = (float*)d_ws;
        build_cost_kernel<<<dim3(Q_ / 64, B_), 256, 0, stream>>>(obj, cd, gi, ct);
        matcher_kernel<true><<<B_, T_, 0, stream>>>(obj, cd, gi, ngt, ct, out0, out1);
    } else {
        matcher_kernel<false><<<B_, T_, 0, stream>>>(obj, cd, gi, ngt, nullptr, out0, out1);
    }
}